// Round 13
// baseline (4817.805 us; speedup 1.0000x reference)
//
#include <hip/hip_runtime.h>

typedef float f4 __attribute__((ext_vector_type(4)));

#define EPSF 1e-5f
#define CIN   256
#define COUT  512
#define HIN   28
#define WIN_  28
#define HO    14
#define WO    14
#define HWO   196
#define NPIX  6272              // 32*14*14 (one app)
#define MROWS 31360             // 5 apps * NPIX
#define MTIL  245               // 31360/128 exact

#define BMr  128                // rows per block
#define BNc  64                 // oc per block (2 wave-halves of 32)
#define BNh  32                 // oc per thread

// ---------------- prep kernels ----------------

__global__ __launch_bounds__(256)
void fold_bias_k(const float* __restrict__ g, const float* __restrict__ b,
                 const float* __restrict__ m, const float* __restrict__ v,
                 float* __restrict__ out)
{
  int oc = blockIdx.x * 256 + threadIdx.x;
  if (oc < COUT) {
    float s = g[oc] / sqrtf(v[oc] + EPSF);
    out[oc] = b[oc] - m[oc] * s;
  }
}

__global__ __launch_bounds__(256)
void fold_w_k(const float* __restrict__ w, const float* __restrict__ g,
              const float* __restrict__ v, float* __restrict__ out,
              int Ci, int taps)
{
  int idx = blockIdx.x * 256 + threadIdx.x;
  int total = taps * Ci * COUT;
  if (idx >= total) return;
  int oc  = idx % COUT;
  int c   = (idx / COUT) % Ci;
  int tap = idx / (COUT * Ci);
  float s = g[oc] / sqrtf(v[oc] + EPSF);
  out[idx] = w[((size_t)oc * Ci + c) * taps + tap] * s;
}

// ---------------- conv1 batched over 5 apps (3x3 s2 p1) ----------------
// LDS-free, barrier-free: each thread owns 1 row x 32 oc; A gathered directly
// from NCHW global (L1/L2-served); weights via SGPR-uniform s_load broadcast.
// blockIdx.x = oc-tile (8, XCD-pinned weights); blockIdx.y = M-tile (245).

__global__ __launch_bounds__(256)
void conv1b_k(const float* __restrict__ XS,   // inp_s (4,32,256,28,28)
              const float* __restrict__ XC,   // inp_c (32,256,28,28)
              const float* __restrict__ W1,   // [tap][c][oc]
              float* __restrict__ IO)         // [31360][512]
{
  const int tid  = threadIdx.x;
  const int half = __builtin_amdgcn_readfirstlane(tid >> 7);  // wave-uniform -> SGPR
  const int oc0  = blockIdx.x * BNc + half * BNh;
  const int tl   = tid & 127;
  const int row  = blockIdx.y * BMr + tl;
  const int app  = blockIdx.y / 49;           // 49 M-tiles per app -> block-uniform
  const int pp   = row - app * NPIX;
  const int b    = pp / HWO;
  const int hw   = pp - b * HWO;
  const int ho   = hw / WO, wo = hw - ho * WO;

  const float* xb = (app < 4) ? (XS + (size_t)(app * 32 + b) * (CIN * 784))
                              : (XC + (size_t)b * (CIN * 784));

  float acc[BNh];
  #pragma unroll
  for (int j = 0; j < BNh; j++) acc[j] = 0.f;

  for (int tap = 0; tap < 9; ++tap) {
    int kh = tap / 3, kw = tap - kh * 3;
    int hi = 2 * ho + kh - 1, wi = 2 * wo + kw - 1;
    if ((unsigned)hi >= (unsigned)HIN || (unsigned)wi >= (unsigned)WIN_) continue;
    const float* xp = xb + hi * WIN_ + wi;
    const float* wt = W1 + (size_t)tap * CIN * COUT + oc0;

    f4 cur;
    #pragma unroll
    for (int j = 0; j < 4; j++) cur[j] = xp[(size_t)j * 784];
    for (int c4 = 0; c4 < CIN / 4; ++c4) {
      f4 nxt;
      if (c4 + 1 < CIN / 4) {
        #pragma unroll
        for (int j = 0; j < 4; j++) nxt[j] = xp[(size_t)(c4 * 4 + 4 + j) * 784];
      }
      #pragma unroll
      for (int j = 0; j < 4; j++) {
        float a = cur[j];
        const float* __restrict__ wr = wt + (size_t)(c4 * 4 + j) * COUT;  // SGPR-uniform
        #pragma unroll
        for (int jj = 0; jj < BNh; jj++) acc[jj] = fmaf(a, wr[jj], acc[jj]);
      }
      cur = nxt;
    }
  }

  #pragma unroll
  for (int j = 0; j < BNh; j += 4) {
    f4 v = {acc[j], acc[j + 1], acc[j + 2], acc[j + 3]};
    *(f4*)&IO[(size_t)row * COUT + oc0 + j] = v;
  }
}

// ---------------- layer-1 scan ----------------

__global__ __launch_bounds__(256)
void scan1_k(const float* __restrict__ IO, const float* __restrict__ b1v,
             const float* __restrict__ vth1,
             unsigned char* __restrict__ SP,   // [4][NPIX][512] u8
             float* __restrict__ ACT)          // [NPIX][512]
{
  int idx = blockIdx.x * 256 + threadIdx.x;
  int oc = idx & 511, pix = idx >> 9;
  int hw = pix % HWO;
  float b1 = b1v[oc], vt = vth1[oc * HWO + hw];
  float mem = 0.f; int m1 = 0;
  #pragma unroll
  for (int t = 0; t < 4; ++t) {
    float cur = IO[((size_t)t * NPIX + pix) * 512 + oc] + b1;
    mem += cur;
    float sp = (mem >= vt) ? 1.f : 0.f;
    mem -= sp * vt;
    m1 += (sp > 0.f) ? 1 : 0;
    SP[((size_t)t * NPIX + pix) * 512 + oc] = (unsigned char)sp;
  }
  float a = IO[((size_t)4 * NPIX + pix) * 512 + oc] + b1;
  a = a > 0.f ? a : 0.f;
  ACT[(size_t)pix * 512 + oc] = (m1 > 0) ? a : 0.f;
}

// ---------------- conv2 batched (3x3 s1 p1) + ds (1x1 s2) fused ----------------
// Same LDS-free structure. Spike apps read u8 planes; ANN app reads fp32 ACT.

__global__ __launch_bounds__(256)
void conv2b_k(const unsigned char* __restrict__ SP,
              const float* __restrict__ ACT,
              const float* __restrict__ XS,
              const float* __restrict__ XC,
              const float* __restrict__ W2,
              const float* __restrict__ WD,
              float* __restrict__ IO)
{
  const int tid  = threadIdx.x;
  const int half = __builtin_amdgcn_readfirstlane(tid >> 7);
  const int oc0  = blockIdx.x * BNc + half * BNh;
  const int tl   = tid & 127;
  const int row  = blockIdx.y * BMr + tl;
  const int app  = blockIdx.y / 49;           // block-uniform
  const int pp   = row - app * NPIX;
  const int b    = pp / HWO;
  const int hw   = pp - b * HWO;
  const int ho   = hw / WO, wo = hw - ho * WO;

  float acc[BNh];
  #pragma unroll
  for (int j = 0; j < BNh; j++) acc[j] = 0.f;

  if (app < 4) {
    const unsigned char* spb = SP + (size_t)app * NPIX * 512;
    for (int tap = 0; tap < 9; ++tap) {
      int kh = tap / 3, kw = tap - kh * 3;
      int hi = ho + kh - 1, wi = wo + kw - 1;
      if ((unsigned)hi >= (unsigned)HO || (unsigned)wi >= (unsigned)WO) continue;
      const unsigned char* src = spb + (size_t)(b * HWO + hi * WO + wi) * 512;
      const float* wt = W2 + (size_t)tap * COUT * COUT + oc0;

      unsigned cur = *(const unsigned*)(src);
      for (int c4 = 0; c4 < COUT / 4; ++c4) {
        unsigned nxt = (c4 + 1 < COUT / 4) ? *(const unsigned*)(src + c4 * 4 + 4) : 0u;
        #pragma unroll
        for (int j = 0; j < 4; j++) {
          float a = (float)((cur >> (8 * j)) & 255u);
          const float* __restrict__ wr = wt + (size_t)(c4 * 4 + j) * COUT;
          #pragma unroll
          for (int jj = 0; jj < BNh; jj++) acc[jj] = fmaf(a, wr[jj], acc[jj]);
        }
        cur = nxt;
      }
    }
  } else {
    for (int tap = 0; tap < 9; ++tap) {
      int kh = tap / 3, kw = tap - kh * 3;
      int hi = ho + kh - 1, wi = wo + kw - 1;
      if ((unsigned)hi >= (unsigned)HO || (unsigned)wi >= (unsigned)WO) continue;
      const float* src = ACT + (size_t)(b * HWO + hi * WO + wi) * 512;
      const float* wt = W2 + (size_t)tap * COUT * COUT + oc0;

      f4 cur = *(const f4*)(src);
      for (int c4 = 0; c4 < COUT / 4; ++c4) {
        f4 nxt;
        if (c4 + 1 < COUT / 4) nxt = *(const f4*)(src + c4 * 4 + 4);
        #pragma unroll
        for (int j = 0; j < 4; j++) {
          float a = cur[j];
          const float* __restrict__ wr = wt + (size_t)(c4 * 4 + j) * COUT;
          #pragma unroll
          for (int jj = 0; jj < BNh; jj++) acc[jj] = fmaf(a, wr[jj], acc[jj]);
        }
        cur = nxt;
      }
    }
  }

  // downsample 1x1 s2 on NCHW input
  {
    const float* xb = (app < 4) ? (XS + (size_t)(app * 32 + b) * (CIN * 784))
                                : (XC + (size_t)b * (CIN * 784));
    const float* xp = xb + 2 * ho * WIN_ + 2 * wo;
    f4 cur;
    #pragma unroll
    for (int j = 0; j < 4; j++) cur[j] = xp[(size_t)j * 784];
    for (int c4 = 0; c4 < CIN / 4; ++c4) {
      f4 nxt;
      if (c4 + 1 < CIN / 4) {
        #pragma unroll
        for (int j = 0; j < 4; j++) nxt[j] = xp[(size_t)(c4 * 4 + 4 + j) * 784];
      }
      #pragma unroll
      for (int j = 0; j < 4; j++) {
        float a = cur[j];
        const float* __restrict__ wr = WD + (size_t)(c4 * 4 + j) * COUT + oc0;
        #pragma unroll
        for (int jj = 0; jj < BNh; jj++) acc[jj] = fmaf(a, wr[jj], acc[jj]);
      }
      cur = nxt;
    }
  }

  #pragma unroll
  for (int j = 0; j < BNh; j += 4) {
    f4 v = {acc[j], acc[j + 1], acc[j + 2], acc[j + 3]};
    *(f4*)&IO[(size_t)row * COUT + oc0 + j] = v;
  }
}

// ---------------- final scan + outputs (NCHW) ----------------

__global__ __launch_bounds__(256)
void final_k(const float* __restrict__ IO, const float* __restrict__ b2v,
             const float* __restrict__ bdv, const float* __restrict__ vthif,
             float* __restrict__ out0, float* __restrict__ out1,
             float* __restrict__ out2)
{
  int idx = blockIdx.x * 256 + threadIdx.x;
  int oc = idx & 511, pix = idx >> 9;
  int hw = pix % HWO, b = pix / HWO;
  float bias = b2v[oc] + bdv[oc];
  float vt = vthif[oc * HWO + hw];
  float memf = 0.f; int m3 = 0; float o3 = 0.f, os3 = 0.f;
  #pragma unroll
  for (int t = 0; t < 4; ++t) {
    float os = IO[((size_t)t * NPIX + pix) * 512 + oc] + bias;
    memf += os;
    float sp = (memf >= vt) ? 1.f : 0.f;
    memf -= sp * vt;
    m3 += (sp > 0.f) ? 1 : 0;
    if (t == 3) { o3 = sp; os3 = os; }
  }
  size_t oidx = ((size_t)b * COUT + oc) * HWO + hw;
  out0[oidx] = o3;
  out1[oidx] = os3;
  float av = IO[((size_t)4 * NPIX + pix) * 512 + oc] + bias;
  av = av > 0.f ? av : 0.f;
  out2[oidx] = (m3 > 0) ? av : 0.f;
}

// ---------------- launcher ----------------

extern "C" void kernel_launch(void* const* d_in, const int* in_sizes, int n_in,
                              void* d_out, int out_size, void* d_ws, size_t ws_size,
                              hipStream_t stream)
{
  const float* inp_s = (const float*)d_in[0];
  const float* inp_c = (const float*)d_in[2];
  const float* w1    = (const float*)d_in[3];
  const float* w2    = (const float*)d_in[4];
  const float* wd    = (const float*)d_in[5];
  const float* bn1g = (const float*)d_in[6],  *bn1b = (const float*)d_in[7];
  const float* bn1m = (const float*)d_in[8],  *bn1v = (const float*)d_in[9];
  const float* bn2g = (const float*)d_in[10], *bn2b = (const float*)d_in[11];
  const float* bn2m = (const float*)d_in[12], *bn2v = (const float*)d_in[13];
  const float* dsg  = (const float*)d_in[14], *dsb  = (const float*)d_in[15];
  const float* dsm  = (const float*)d_in[16], *dsv  = (const float*)d_in[17];
  const float* vth1  = (const float*)d_in[18];
  const float* vthif = (const float*)d_in[21];

  float* ws = (float*)d_ws;
  size_t off = 0;
  float* W1T = ws + off; off += (size_t)9 * CIN * COUT;
  float* W2T = ws + off; off += (size_t)9 * COUT * COUT;
  float* WDT = ws + off; off += (size_t)CIN * COUT;
  float* B1V = ws + off; off += COUT;
  float* B2V = ws + off; off += COUT;
  float* BDV = ws + off; off += COUT;
  float* IO  = ws + off; off += (size_t)MROWS * COUT;
  float* ACT = ws + off; off += (size_t)NPIX * COUT;
  unsigned char* SP = (unsigned char*)(ws + off);
  // total ~104.6 MB, under the R1-proven 117.4 MB bound

  float* out0 = (float*)d_out;
  float* out1 = out0 + (size_t)NPIX * COUT;
  float* out2 = out1 + (size_t)NPIX * COUT;

  fold_bias_k<<<2, 256, 0, stream>>>(bn1g, bn1b, bn1m, bn1v, B1V);
  fold_bias_k<<<2, 256, 0, stream>>>(bn2g, bn2b, bn2m, bn2v, B2V);
  fold_bias_k<<<2, 256, 0, stream>>>(dsg,  dsb,  dsm,  dsv,  BDV);
  fold_w_k<<<(9 * CIN * COUT + 255) / 256, 256, 0, stream>>>(w1, bn1g, bn1v, W1T, CIN, 9);
  fold_w_k<<<(9 * COUT * COUT + 255) / 256, 256, 0, stream>>>(w2, bn2g, bn2v, W2T, COUT, 9);
  fold_w_k<<<(CIN * COUT + 255) / 256, 256, 0, stream>>>(wd, dsg, dsv, WDT, CIN, 1);

  dim3 cgrid(COUT / BNc, MTIL);                 // 8 x 245 : x = oc-slice -> XCD-pinned
  const int scanGrid = (NPIX * COUT) / 256;

  conv1b_k<<<cgrid, 256, 0, stream>>>(inp_s, inp_c, W1T, IO);
  scan1_k<<<scanGrid, 256, 0, stream>>>(IO, B1V, vth1, SP, ACT);
  conv2b_k<<<cgrid, 256, 0, stream>>>(SP, ACT, inp_s, inp_c, W2T, WDT, IO);
  final_k<<<scanGrid, 256, 0, stream>>>(IO, B2V, BDV, vthif, out0, out1, out2);
}

// Round 14
// 2899.189 us; speedup vs baseline: 1.6618x; 1.6618x over previous
//
#include <hip/hip_runtime.h>

typedef float f4 __attribute__((ext_vector_type(4)));

#define EPSF 1e-5f
#define CIN   256
#define COUT  512
#define HIN   28
#define WIN_  28
#define HO    14
#define WO    14
#define HWO   196
#define NPIX  6272              // 32*14*14 (one app)
#define MROWS 31360             // 5 apps * NPIX

#define BMr  64                 // rows per block
#define BNcT 128                // oc per block
#define BKC  16                 // k per step
#define LRA  64                 // A[k][row] stride
#define LRW  132                // W[k][oc] stride (pad -> 2-way max)

#define NS1  144                // conv1: 9 taps * 16 chunks of 16
#define NS2  304                // conv2: 288 conv + 16 ds

// ---------------- prep kernels ----------------

__global__ __launch_bounds__(256)
void fold_bias_k(const float* __restrict__ g, const float* __restrict__ b,
                 const float* __restrict__ m, const float* __restrict__ v,
                 float* __restrict__ out)
{
  int oc = blockIdx.x * 256 + threadIdx.x;
  if (oc < COUT) {
    float s = g[oc] / sqrtf(v[oc] + EPSF);
    out[oc] = b[oc] - m[oc] * s;
  }
}

__global__ __launch_bounds__(256)
void fold_w_k(const float* __restrict__ w, const float* __restrict__ g,
              const float* __restrict__ v, float* __restrict__ out,
              int Ci, int taps)
{
  int idx = blockIdx.x * 256 + threadIdx.x;
  int total = taps * Ci * COUT;
  if (idx >= total) return;
  int oc  = idx % COUT;
  int c   = (idx / COUT) % Ci;
  int tap = idx / (COUT * Ci);
  float s = g[oc] / sqrtf(v[oc] + EPSF);
  out[idx] = w[((size_t)oc * Ci + c) * taps + tap] * s;
}

// ---------------- conv1 batched over 5 apps (3x3 s2 p1) ----------------
// Register-tiled GEMM: 64x128 tile, thread = 4 rows x 8 oc.
// blockIdx.x = oc-tile (4); blockIdx.y = M-tile (490).

__global__ __launch_bounds__(256)
void conv1b_k(const float* __restrict__ XS,   // inp_s (4,32,256,28,28)
              const float* __restrict__ XC,   // inp_c (32,256,28,28)
              const float* __restrict__ W1,   // [tap][c][oc]
              float* __restrict__ IO)         // [31360][512]
{
  __shared__ float lA[BKC * LRA];
  __shared__ float lW[BKC * LRW];
  const int tid = threadIdx.x;
  const int tr = tid >> 4;          // 0..15 -> rows tr*4..+3
  const int tc = tid & 15;          // oc tc*4 and 64+tc*4
  const int oc0 = blockIdx.x * BNcT;
  const int rowBase = blockIdx.y * BMr;
  const int app = blockIdx.y / 98;  // 98 M-tiles per app (block-uniform)

  // A staging role: row grow, k-quad kq
  const int grow = tid & 63;
  const int kq = tid >> 6;
  {
  }
  const int r = rowBase + grow;
  const int pp = r - app * NPIX;
  const int b = pp / HWO;
  const int hw = pp - b * HWO;
  const int ho = hw / WO, wo = hw - ho * WO;
  const float* xb = (app < 4) ? (XS + (size_t)(app * 32 + b) * (CIN * 784))
                              : (XC + (size_t)b * (CIN * 784));

  // W staging role
  const int wk = tid >> 4;          // k row 0..15
  const int woc = (tid & 15) * 8;   // 8 oc

  float acc[4][8];
  #pragma unroll
  for (int i = 0; i < 4; i++)
    #pragma unroll
    for (int j = 0; j < 8; j++) acc[i][j] = 0.f;

  f4 ga, gw0, gw1;

  auto issue = [&](int s) {
    int tap = s >> 4, c0 = (s & 15) << 4;
    int kh = tap / 3, kw = tap - kh * 3;
    int hi = 2 * ho + kh - 1, wi = 2 * wo + kw - 1;
    bool v = ((unsigned)hi < (unsigned)HIN) && ((unsigned)wi < (unsigned)WIN_);
    const float* xp = xb + (size_t)(c0 + kq * 4) * 784 + hi * WIN_ + wi;
    #pragma unroll
    for (int j = 0; j < 4; j++) ga[j] = v ? xp[(size_t)j * 784] : 0.f;
    const float* wp = W1 + ((size_t)tap * CIN + c0 + wk) * COUT + oc0 + woc;
    gw0 = *(const f4*)wp;
    gw1 = *(const f4*)(wp + 4);
  };

  auto write_lds = [&]() {
    #pragma unroll
    for (int j = 0; j < 4; j++) lA[(kq * 4 + j) * LRA + grow] = ga[j];
    *(f4*)&lW[wk * LRW + woc] = gw0;
    *(f4*)&lW[wk * LRW + woc + 4] = gw1;
  };

  auto compute = [&]() {
    #pragma unroll
    for (int k = 0; k < BKC; k++) {
      f4 a  = *(const f4*)&lA[k * LRA + tr * 4];
      f4 w0 = *(const f4*)&lW[k * LRW + tc * 4];
      f4 w1 = *(const f4*)&lW[k * LRW + 64 + tc * 4];
      #pragma unroll
      for (int i = 0; i < 4; i++)
        #pragma unroll
        for (int j = 0; j < 4; j++) {
          acc[i][j]     = fmaf(a[i], w0[j], acc[i][j]);
          acc[i][j + 4] = fmaf(a[i], w1[j], acc[i][j + 4]);
        }
    }
  };

  issue(0);
  for (int s = 0; s < NS1; ++s) {
    __syncthreads();
    write_lds();
    __syncthreads();
    if (s + 1 < NS1) issue(s + 1);
    compute();
  }

  #pragma unroll
  for (int i = 0; i < 4; i++) {
    int row = rowBase + tr * 4 + i;
    f4 v0 = {acc[i][0], acc[i][1], acc[i][2], acc[i][3]};
    f4 v1 = {acc[i][4], acc[i][5], acc[i][6], acc[i][7]};
    *(f4*)&IO[(size_t)row * COUT + oc0 + tc * 4] = v0;
    *(f4*)&IO[(size_t)row * COUT + oc0 + 64 + tc * 4] = v1;
  }
}

// ---------------- layer-1 scan ----------------

__global__ __launch_bounds__(256)
void scan1_k(const float* __restrict__ IO, const float* __restrict__ b1v,
             const float* __restrict__ vth1,
             unsigned char* __restrict__ SP,   // [4][NPIX][512] u8
             float* __restrict__ ACT)          // [NPIX][512]
{
  int idx = blockIdx.x * 256 + threadIdx.x;
  int oc = idx & 511, pix = idx >> 9;
  int hw = pix % HWO;
  float b1 = b1v[oc], vt = vth1[oc * HWO + hw];
  float mem = 0.f; int m1 = 0;
  #pragma unroll
  for (int t = 0; t < 4; ++t) {
    float cur = IO[((size_t)t * NPIX + pix) * 512 + oc] + b1;
    mem += cur;
    float sp = (mem >= vt) ? 1.f : 0.f;
    mem -= sp * vt;
    m1 += (sp > 0.f) ? 1 : 0;
    SP[((size_t)t * NPIX + pix) * 512 + oc] = (unsigned char)sp;
  }
  float a = IO[((size_t)4 * NPIX + pix) * 512 + oc] + b1;
  a = a > 0.f ? a : 0.f;
  ACT[(size_t)pix * 512 + oc] = (m1 > 0) ? a : 0.f;
}

// ---------------- conv2 batched (3x3 s1 p1) + ds (1x1 s2) fused ----------------

__global__ __launch_bounds__(256)
void conv2b_k(const unsigned char* __restrict__ SP,
              const float* __restrict__ ACT,
              const float* __restrict__ XS,
              const float* __restrict__ XC,
              const float* __restrict__ W2,
              const float* __restrict__ WD,
              float* __restrict__ IO)
{
  __shared__ float lA[BKC * LRA];
  __shared__ float lW[BKC * LRW];
  const int tid = threadIdx.x;
  const int tr = tid >> 4;
  const int tc = tid & 15;
  const int oc0 = blockIdx.x * BNcT;
  const int rowBase = blockIdx.y * BMr;
  const int app = blockIdx.y / 98;

  const int grow = tid & 63;
  const int kq = tid >> 6;
  const int r = rowBase + grow;
  const int pp = r - app * NPIX;
  const int b = pp / HWO;
  const int hw = pp - b * HWO;
  const int ho = hw / WO, wo = hw - ho * WO;
  const float* xb = (app < 4) ? (XS + (size_t)(app * 32 + b) * (CIN * 784))
                              : (XC + (size_t)b * (CIN * 784));
  const unsigned char* spb = SP + (size_t)app * NPIX * 512;

  const int wk = tid >> 4;
  const int woc = (tid & 15) * 8;

  float acc[4][8];
  #pragma unroll
  for (int i = 0; i < 4; i++)
    #pragma unroll
    for (int j = 0; j < 8; j++) acc[i][j] = 0.f;

  f4 ga, gw0, gw1;

  auto issue = [&](int s) {
    if (s < 288) {
      int tap = s >> 5, c0 = (s & 31) << 4;
      int kh = tap / 3, kw = tap - kh * 3;
      int hi = ho + kh - 1, wi = wo + kw - 1;
      bool v = ((unsigned)hi < (unsigned)HO) && ((unsigned)wi < (unsigned)WO);
      int pix2 = b * HWO + hi * WO + wi;
      int c = c0 + kq * 4;
      if (app < 4) {
        unsigned u = 0;
        if (v) u = *(const unsigned*)(spb + (size_t)pix2 * 512 + c);
        #pragma unroll
        for (int j = 0; j < 4; j++) ga[j] = (float)((u >> (8 * j)) & 255u);
      } else {
        f4 val = {0.f, 0.f, 0.f, 0.f};
        if (v) val = *(const f4*)(ACT + (size_t)pix2 * 512 + c);
        ga = val;
      }
      const float* wp = W2 + ((size_t)tap * COUT + c0 + wk) * COUT + oc0 + woc;
      gw0 = *(const f4*)wp;
      gw1 = *(const f4*)(wp + 4);
    } else {
      int c0 = (s - 288) << 4;
      const float* xp = xb + (size_t)(c0 + kq * 4) * 784 + 2 * ho * WIN_ + 2 * wo;
      #pragma unroll
      for (int j = 0; j < 4; j++) ga[j] = xp[(size_t)j * 784];
      const float* wp = WD + (size_t)(c0 + wk) * COUT + oc0 + woc;
      gw0 = *(const f4*)wp;
      gw1 = *(const f4*)(wp + 4);
    }
  };

  auto write_lds = [&]() {
    #pragma unroll
    for (int j = 0; j < 4; j++) lA[(kq * 4 + j) * LRA + grow] = ga[j];
    *(f4*)&lW[wk * LRW + woc] = gw0;
    *(f4*)&lW[wk * LRW + woc + 4] = gw1;
  };

  auto compute = [&]() {
    #pragma unroll
    for (int k = 0; k < BKC; k++) {
      f4 a  = *(const f4*)&lA[k * LRA + tr * 4];
      f4 w0 = *(const f4*)&lW[k * LRW + tc * 4];
      f4 w1 = *(const f4*)&lW[k * LRW + 64 + tc * 4];
      #pragma unroll
      for (int i = 0; i < 4; i++)
        #pragma unroll
        for (int j = 0; j < 4; j++) {
          acc[i][j]     = fmaf(a[i], w0[j], acc[i][j]);
          acc[i][j + 4] = fmaf(a[i], w1[j], acc[i][j + 4]);
        }
    }
  };

  issue(0);
  for (int s = 0; s < NS2; ++s) {
    __syncthreads();
    write_lds();
    __syncthreads();
    if (s + 1 < NS2) issue(s + 1);
    compute();
  }

  #pragma unroll
  for (int i = 0; i < 4; i++) {
    int row = rowBase + tr * 4 + i;
    f4 v0 = {acc[i][0], acc[i][1], acc[i][2], acc[i][3]};
    f4 v1 = {acc[i][4], acc[i][5], acc[i][6], acc[i][7]};
    *(f4*)&IO[(size_t)row * COUT + oc0 + tc * 4] = v0;
    *(f4*)&IO[(size_t)row * COUT + oc0 + 64 + tc * 4] = v1;
  }
}

// ---------------- final scan + outputs (NCHW) ----------------

__global__ __launch_bounds__(256)
void final_k(const float* __restrict__ IO, const float* __restrict__ b2v,
             const float* __restrict__ bdv, const float* __restrict__ vthif,
             float* __restrict__ out0, float* __restrict__ out1,
             float* __restrict__ out2)
{
  int idx = blockIdx.x * 256 + threadIdx.x;
  int oc = idx & 511, pix = idx >> 9;
  int hw = pix % HWO, b = pix / HWO;
  float bias = b2v[oc] + bdv[oc];
  float vt = vthif[oc * HWO + hw];
  float memf = 0.f; int m3 = 0; float o3 = 0.f, os3 = 0.f;
  #pragma unroll
  for (int t = 0; t < 4; ++t) {
    float os = IO[((size_t)t * NPIX + pix) * 512 + oc] + bias;
    memf += os;
    float sp = (memf >= vt) ? 1.f : 0.f;
    memf -= sp * vt;
    m3 += (sp > 0.f) ? 1 : 0;
    if (t == 3) { o3 = sp; os3 = os; }
  }
  size_t oidx = ((size_t)b * COUT + oc) * HWO + hw;
  out0[oidx] = o3;
  out1[oidx] = os3;
  float av = IO[((size_t)4 * NPIX + pix) * 512 + oc] + bias;
  av = av > 0.f ? av : 0.f;
  out2[oidx] = (m3 > 0) ? av : 0.f;
}

// ---------------- launcher ----------------

extern "C" void kernel_launch(void* const* d_in, const int* in_sizes, int n_in,
                              void* d_out, int out_size, void* d_ws, size_t ws_size,
                              hipStream_t stream)
{
  const float* inp_s = (const float*)d_in[0];
  const float* inp_c = (const float*)d_in[2];
  const float* w1    = (const float*)d_in[3];
  const float* w2    = (const float*)d_in[4];
  const float* wd    = (const float*)d_in[5];
  const float* bn1g = (const float*)d_in[6],  *bn1b = (const float*)d_in[7];
  const float* bn1m = (const float*)d_in[8],  *bn1v = (const float*)d_in[9];
  const float* bn2g = (const float*)d_in[10], *bn2b = (const float*)d_in[11];
  const float* bn2m = (const float*)d_in[12], *bn2v = (const float*)d_in[13];
  const float* dsg  = (const float*)d_in[14], *dsb  = (const float*)d_in[15];
  const float* dsm  = (const float*)d_in[16], *dsv  = (const float*)d_in[17];
  const float* vth1  = (const float*)d_in[18];
  const float* vthif = (const float*)d_in[21];

  float* ws = (float*)d_ws;
  size_t off = 0;
  float* W1T = ws + off; off += (size_t)9 * CIN * COUT;
  float* W2T = ws + off; off += (size_t)9 * COUT * COUT;
  float* WDT = ws + off; off += (size_t)CIN * COUT;
  float* B1V = ws + off; off += COUT;
  float* B2V = ws + off; off += COUT;
  float* BDV = ws + off; off += COUT;
  float* IO  = ws + off; off += (size_t)MROWS * COUT;
  float* ACT = ws + off; off += (size_t)NPIX * COUT;
  unsigned char* SP = (unsigned char*)(ws + off);
  // total ~104.6 MB, under the R1-proven 117.4 MB bound

  float* out0 = (float*)d_out;
  float* out1 = out0 + (size_t)NPIX * COUT;
  float* out2 = out1 + (size_t)NPIX * COUT;

  fold_bias_k<<<2, 256, 0, stream>>>(bn1g, bn1b, bn1m, bn1v, B1V);
  fold_bias_k<<<2, 256, 0, stream>>>(bn2g, bn2b, bn2m, bn2v, B2V);
  fold_bias_k<<<2, 256, 0, stream>>>(dsg,  dsb,  dsm,  dsv,  BDV);
  fold_w_k<<<(9 * CIN * COUT + 255) / 256, 256, 0, stream>>>(w1, bn1g, bn1v, W1T, CIN, 9);
  fold_w_k<<<(9 * COUT * COUT + 255) / 256, 256, 0, stream>>>(w2, bn2g, bn2v, W2T, COUT, 9);
  fold_w_k<<<(CIN * COUT + 255) / 256, 256, 0, stream>>>(wd, dsg, dsv, WDT, CIN, 1);

  dim3 cgrid(COUT / BNcT, MROWS / BMr);         // 4 x 490
  const int scanGrid = (NPIX * COUT) / 256;

  conv1b_k<<<cgrid, 256, 0, stream>>>(inp_s, inp_c, W1T, IO);
  scan1_k<<<scanGrid, 256, 0, stream>>>(IO, B1V, vth1, SP, ACT);
  conv2b_k<<<cgrid, 256, 0, stream>>>(SP, ACT, inp_s, inp_c, W2T, WDT, IO);
  final_k<<<scanGrid, 256, 0, stream>>>(IO, B2V, BDV, vthif, out0, out1, out2);
}

// Round 15
// 2740.007 us; speedup vs baseline: 1.7583x; 1.0581x over previous
//
#include <hip/hip_runtime.h>

typedef float f4 __attribute__((ext_vector_type(4)));

#define EPSF 1e-5f
#define CIN   256
#define COUT  512
#define HIN   28
#define WIN_  28
#define HO    14
#define WO    14
#define HWO   196
#define NPIX  6272              // 32*14*14 (one app)
#define MROWS 31360             // 5 apps * NPIX

#define BMr  128                // rows per block
#define BNcT 128                // oc per block
#define BKC  16                 // k per step
#define LRA  128                // A[k][row] stride
#define LRW  132                // W[k][oc] stride (pad)

#define NS1  144                // conv1: 9 taps * 16 chunks of 16
#define NS2  304                // conv2: 288 conv + 16 ds

// ---------------- prep kernels ----------------

__global__ __launch_bounds__(256)
void fold_bias_k(const float* __restrict__ g, const float* __restrict__ b,
                 const float* __restrict__ m, const float* __restrict__ v,
                 float* __restrict__ out)
{
  int oc = blockIdx.x * 256 + threadIdx.x;
  if (oc < COUT) {
    float s = g[oc] / sqrtf(v[oc] + EPSF);
    out[oc] = b[oc] - m[oc] * s;
  }
}

__global__ __launch_bounds__(256)
void fold_w_k(const float* __restrict__ w, const float* __restrict__ g,
              const float* __restrict__ v, float* __restrict__ out,
              int Ci, int taps)
{
  int idx = blockIdx.x * 256 + threadIdx.x;
  int total = taps * Ci * COUT;
  if (idx >= total) return;
  int oc  = idx % COUT;
  int c   = (idx / COUT) % Ci;
  int tap = idx / (COUT * Ci);
  float s = g[oc] / sqrtf(v[oc] + EPSF);
  out[idx] = w[((size_t)oc * Ci + c) * taps + tap] * s;
}

// ---------------- conv1 batched over 5 apps (3x3 s2 p1) ----------------
// Register-tiled GEMM: 128x128 tile, thread = 8 rows x 8 oc.
// blockIdx.x = oc-tile (4); blockIdx.y = M-tile (245).

__global__ __launch_bounds__(256)
void conv1b_k(const float* __restrict__ XS,   // inp_s (4,32,256,28,28)
              const float* __restrict__ XC,   // inp_c (32,256,28,28)
              const float* __restrict__ W1,   // [tap][c][oc]
              float* __restrict__ IO)         // [31360][512]
{
  __shared__ float lA[BKC * LRA];
  __shared__ float lW[BKC * LRW];
  const int tid = threadIdx.x;
  const int tr = tid >> 4;          // 0..15 -> rows tr*8..+7
  const int tc = tid & 15;          // oc tc*4 and 64+tc*4
  const int oc0 = blockIdx.x * BNcT;
  const int rowBase = blockIdx.y * BMr;
  const int app = blockIdx.y / 49;  // block-uniform

  // A staging role: one row, 8 k values
  const int grow = tid & 127;
  const int kq = tid >> 7;          // 0..1 -> k = kq*8 + j
  const int r = rowBase + grow;
  const int pp = r - app * NPIX;
  const int b = pp / HWO;
  const int hw = pp - b * HWO;
  const int ho = hw / WO, wo = hw - ho * WO;
  const float* xb = (app < 4) ? (XS + (size_t)(app * 32 + b) * (CIN * 784))
                              : (XC + (size_t)b * (CIN * 784));

  // W staging role
  const int wk = tid >> 4;          // k row 0..15
  const int woc = (tid & 15) * 8;   // 8 oc

  float acc[8][8];
  #pragma unroll
  for (int i = 0; i < 8; i++)
    #pragma unroll
    for (int j = 0; j < 8; j++) acc[i][j] = 0.f;

  float ga[8]; f4 gw0, gw1;

  auto issue = [&](int s) {
    int tap = s >> 4, c0 = (s & 15) << 4;
    int kh = tap / 3, kw = tap - kh * 3;
    int hi = 2 * ho + kh - 1, wi = 2 * wo + kw - 1;
    bool v = ((unsigned)hi < (unsigned)HIN) && ((unsigned)wi < (unsigned)WIN_);
    const float* xp = xb + (size_t)(c0 + kq * 8) * 784 + hi * WIN_ + wi;
    #pragma unroll
    for (int j = 0; j < 8; j++) ga[j] = v ? xp[(size_t)j * 784] : 0.f;
    const float* wp = W1 + ((size_t)tap * CIN + c0 + wk) * COUT + oc0 + woc;
    gw0 = *(const f4*)wp;
    gw1 = *(const f4*)(wp + 4);
  };

  auto write_lds = [&]() {
    #pragma unroll
    for (int j = 0; j < 8; j++) lA[(kq * 8 + j) * LRA + grow] = ga[j];
    *(f4*)&lW[wk * LRW + woc] = gw0;
    *(f4*)&lW[wk * LRW + woc + 4] = gw1;
  };

  auto compute = [&]() {
    #pragma unroll
    for (int k = 0; k < BKC; k++) {
      f4 a0 = *(const f4*)&lA[k * LRA + tr * 8];
      f4 a1 = *(const f4*)&lA[k * LRA + tr * 8 + 4];
      f4 w0 = *(const f4*)&lW[k * LRW + tc * 4];
      f4 w1 = *(const f4*)&lW[k * LRW + 64 + tc * 4];
      #pragma unroll
      for (int i = 0; i < 4; i++)
        #pragma unroll
        for (int j = 0; j < 4; j++) {
          acc[i][j]         = fmaf(a0[i], w0[j], acc[i][j]);
          acc[i][j + 4]     = fmaf(a0[i], w1[j], acc[i][j + 4]);
          acc[i + 4][j]     = fmaf(a1[i], w0[j], acc[i + 4][j]);
          acc[i + 4][j + 4] = fmaf(a1[i], w1[j], acc[i + 4][j + 4]);
        }
    }
  };

  issue(0);
  for (int s = 0; s < NS1; ++s) {
    __syncthreads();
    write_lds();
    __syncthreads();
    if (s + 1 < NS1) issue(s + 1);
    compute();
  }

  #pragma unroll
  for (int i = 0; i < 8; i++) {
    int row = rowBase + tr * 8 + i;
    f4 v0 = {acc[i][0], acc[i][1], acc[i][2], acc[i][3]};
    f4 v1 = {acc[i][4], acc[i][5], acc[i][6], acc[i][7]};
    *(f4*)&IO[(size_t)row * COUT + oc0 + tc * 4] = v0;
    *(f4*)&IO[(size_t)row * COUT + oc0 + 64 + tc * 4] = v1;
  }
}

// ---------------- layer-1 scan ----------------

__global__ __launch_bounds__(256)
void scan1_k(const float* __restrict__ IO, const float* __restrict__ b1v,
             const float* __restrict__ vth1,
             unsigned char* __restrict__ SP,   // [4][NPIX][512] u8
             float* __restrict__ ACT)          // [NPIX][512]
{
  int idx = blockIdx.x * 256 + threadIdx.x;
  int oc = idx & 511, pix = idx >> 9;
  int hw = pix % HWO;
  float b1 = b1v[oc], vt = vth1[oc * HWO + hw];
  float mem = 0.f; int m1 = 0;
  #pragma unroll
  for (int t = 0; t < 4; ++t) {
    float cur = IO[((size_t)t * NPIX + pix) * 512 + oc] + b1;
    mem += cur;
    float sp = (mem >= vt) ? 1.f : 0.f;
    mem -= sp * vt;
    m1 += (sp > 0.f) ? 1 : 0;
    SP[((size_t)t * NPIX + pix) * 512 + oc] = (unsigned char)sp;
  }
  float a = IO[((size_t)4 * NPIX + pix) * 512 + oc] + b1;
  a = a > 0.f ? a : 0.f;
  ACT[(size_t)pix * 512 + oc] = (m1 > 0) ? a : 0.f;
}

// ---------------- conv2 batched (3x3 s1 p1) + ds (1x1 s2) fused ----------------

__global__ __launch_bounds__(256)
void conv2b_k(const unsigned char* __restrict__ SP,
              const float* __restrict__ ACT,
              const float* __restrict__ XS,
              const float* __restrict__ XC,
              const float* __restrict__ W2,
              const float* __restrict__ WD,
              float* __restrict__ IO)
{
  __shared__ float lA[BKC * LRA];
  __shared__ float lW[BKC * LRW];
  const int tid = threadIdx.x;
  const int tr = tid >> 4;
  const int tc = tid & 15;
  const int oc0 = blockIdx.x * BNcT;
  const int rowBase = blockIdx.y * BMr;
  const int app = blockIdx.y / 49;

  const int grow = tid & 127;
  const int kq = tid >> 7;
  const int r = rowBase + grow;
  const int pp = r - app * NPIX;
  const int b = pp / HWO;
  const int hw = pp - b * HWO;
  const int ho = hw / WO, wo = hw - ho * WO;
  const float* xb = (app < 4) ? (XS + (size_t)(app * 32 + b) * (CIN * 784))
                              : (XC + (size_t)b * (CIN * 784));
  const unsigned char* spb = SP + (size_t)app * NPIX * 512;

  const int wk = tid >> 4;
  const int woc = (tid & 15) * 8;

  float acc[8][8];
  #pragma unroll
  for (int i = 0; i < 8; i++)
    #pragma unroll
    for (int j = 0; j < 8; j++) acc[i][j] = 0.f;

  float ga[8]; f4 gw0, gw1;

  auto issue = [&](int s) {
    if (s < 288) {
      int tap = s >> 5, c0 = (s & 31) << 4;
      int kh = tap / 3, kw = tap - kh * 3;
      int hi = ho + kh - 1, wi = wo + kw - 1;
      bool v = ((unsigned)hi < (unsigned)HO) && ((unsigned)wi < (unsigned)WO);
      int pix2 = b * HWO + hi * WO + wi;
      int c = c0 + kq * 8;
      if (app < 4) {
        unsigned u0 = 0, u1 = 0;
        if (v) {
          const unsigned* sp32 = (const unsigned*)(spb + (size_t)pix2 * 512 + c);
          u0 = sp32[0]; u1 = sp32[1];
        }
        #pragma unroll
        for (int j = 0; j < 4; j++) {
          ga[j]     = (float)((u0 >> (8 * j)) & 255u);
          ga[j + 4] = (float)((u1 >> (8 * j)) & 255u);
        }
      } else {
        f4 v0 = {0.f,0.f,0.f,0.f}, v1 = {0.f,0.f,0.f,0.f};
        if (v) {
          const float* ap = ACT + (size_t)pix2 * 512 + c;
          v0 = *(const f4*)ap; v1 = *(const f4*)(ap + 4);
        }
        #pragma unroll
        for (int j = 0; j < 4; j++) { ga[j] = v0[j]; ga[j + 4] = v1[j]; }
      }
      const float* wp = W2 + ((size_t)tap * COUT + c0 + wk) * COUT + oc0 + woc;
      gw0 = *(const f4*)wp;
      gw1 = *(const f4*)(wp + 4);
    } else {
      int c0 = (s - 288) << 4;
      const float* xp = xb + (size_t)(c0 + kq * 8) * 784 + 2 * ho * WIN_ + 2 * wo;
      #pragma unroll
      for (int j = 0; j < 8; j++) ga[j] = xp[(size_t)j * 784];
      const float* wp = WD + (size_t)(c0 + wk) * COUT + oc0 + woc;
      gw0 = *(const f4*)wp;
      gw1 = *(const f4*)(wp + 4);
    }
  };

  auto write_lds = [&]() {
    #pragma unroll
    for (int j = 0; j < 8; j++) lA[(kq * 8 + j) * LRA + grow] = ga[j];
    *(f4*)&lW[wk * LRW + woc] = gw0;
    *(f4*)&lW[wk * LRW + woc + 4] = gw1;
  };

  auto compute = [&]() {
    #pragma unroll
    for (int k = 0; k < BKC; k++) {
      f4 a0 = *(const f4*)&lA[k * LRA + tr * 8];
      f4 a1 = *(const f4*)&lA[k * LRA + tr * 8 + 4];
      f4 w0 = *(const f4*)&lW[k * LRW + tc * 4];
      f4 w1 = *(const f4*)&lW[k * LRW + 64 + tc * 4];
      #pragma unroll
      for (int i = 0; i < 4; i++)
        #pragma unroll
        for (int j = 0; j < 4; j++) {
          acc[i][j]         = fmaf(a0[i], w0[j], acc[i][j]);
          acc[i][j + 4]     = fmaf(a0[i], w1[j], acc[i][j + 4]);
          acc[i + 4][j]     = fmaf(a1[i], w0[j], acc[i + 4][j]);
          acc[i + 4][j + 4] = fmaf(a1[i], w1[j], acc[i + 4][j + 4]);
        }
    }
  };

  issue(0);
  for (int s = 0; s < NS2; ++s) {
    __syncthreads();
    write_lds();
    __syncthreads();
    if (s + 1 < NS2) issue(s + 1);
    compute();
  }

  #pragma unroll
  for (int i = 0; i < 8; i++) {
    int row = rowBase + tr * 8 + i;
    f4 v0 = {acc[i][0], acc[i][1], acc[i][2], acc[i][3]};
    f4 v1 = {acc[i][4], acc[i][5], acc[i][6], acc[i][7]};
    *(f4*)&IO[(size_t)row * COUT + oc0 + tc * 4] = v0;
    *(f4*)&IO[(size_t)row * COUT + oc0 + 64 + tc * 4] = v1;
  }
}

// ---------------- final scan + outputs (NCHW) ----------------

__global__ __launch_bounds__(256)
void final_k(const float* __restrict__ IO, const float* __restrict__ b2v,
             const float* __restrict__ bdv, const float* __restrict__ vthif,
             float* __restrict__ out0, float* __restrict__ out1,
             float* __restrict__ out2)
{
  int idx = blockIdx.x * 256 + threadIdx.x;
  int oc = idx & 511, pix = idx >> 9;
  int hw = pix % HWO, b = pix / HWO;
  float bias = b2v[oc] + bdv[oc];
  float vt = vthif[oc * HWO + hw];
  float memf = 0.f; int m3 = 0; float o3 = 0.f, os3 = 0.f;
  #pragma unroll
  for (int t = 0; t < 4; ++t) {
    float os = IO[((size_t)t * NPIX + pix) * 512 + oc] + bias;
    memf += os;
    float sp = (memf >= vt) ? 1.f : 0.f;
    memf -= sp * vt;
    m3 += (sp > 0.f) ? 1 : 0;
    if (t == 3) { o3 = sp; os3 = os; }
  }
  size_t oidx = ((size_t)b * COUT + oc) * HWO + hw;
  out0[oidx] = o3;
  out1[oidx] = os3;
  float av = IO[((size_t)4 * NPIX + pix) * 512 + oc] + bias;
  av = av > 0.f ? av : 0.f;
  out2[oidx] = (m3 > 0) ? av : 0.f;
}

// ---------------- launcher ----------------

extern "C" void kernel_launch(void* const* d_in, const int* in_sizes, int n_in,
                              void* d_out, int out_size, void* d_ws, size_t ws_size,
                              hipStream_t stream)
{
  const float* inp_s = (const float*)d_in[0];
  const float* inp_c = (const float*)d_in[2];
  const float* w1    = (const float*)d_in[3];
  const float* w2    = (const float*)d_in[4];
  const float* wd    = (const float*)d_in[5];
  const float* bn1g = (const float*)d_in[6],  *bn1b = (const float*)d_in[7];
  const float* bn1m = (const float*)d_in[8],  *bn1v = (const float*)d_in[9];
  const float* bn2g = (const float*)d_in[10], *bn2b = (const float*)d_in[11];
  const float* bn2m = (const float*)d_in[12], *bn2v = (const float*)d_in[13];
  const float* dsg  = (const float*)d_in[14], *dsb  = (const float*)d_in[15];
  const float* dsm  = (const float*)d_in[16], *dsv  = (const float*)d_in[17];
  const float* vth1  = (const float*)d_in[18];
  const float* vthif = (const float*)d_in[21];

  float* ws = (float*)d_ws;
  size_t off = 0;
  float* W1T = ws + off; off += (size_t)9 * CIN * COUT;
  float* W2T = ws + off; off += (size_t)9 * COUT * COUT;
  float* WDT = ws + off; off += (size_t)CIN * COUT;
  float* B1V = ws + off; off += COUT;
  float* B2V = ws + off; off += COUT;
  float* BDV = ws + off; off += COUT;
  float* IO  = ws + off; off += (size_t)MROWS * COUT;
  float* ACT = ws + off; off += (size_t)NPIX * COUT;
  unsigned char* SP = (unsigned char*)(ws + off);
  // total ~104.6 MB, under the R1-proven 117.4 MB bound

  float* out0 = (float*)d_out;
  float* out1 = out0 + (size_t)NPIX * COUT;
  float* out2 = out1 + (size_t)NPIX * COUT;

  fold_bias_k<<<2, 256, 0, stream>>>(bn1g, bn1b, bn1m, bn1v, B1V);
  fold_bias_k<<<2, 256, 0, stream>>>(bn2g, bn2b, bn2m, bn2v, B2V);
  fold_bias_k<<<2, 256, 0, stream>>>(dsg,  dsb,  dsm,  dsv,  BDV);
  fold_w_k<<<(9 * CIN * COUT + 255) / 256, 256, 0, stream>>>(w1, bn1g, bn1v, W1T, CIN, 9);
  fold_w_k<<<(9 * COUT * COUT + 255) / 256, 256, 0, stream>>>(w2, bn2g, bn2v, W2T, COUT, 9);
  fold_w_k<<<(CIN * COUT + 255) / 256, 256, 0, stream>>>(wd, dsg, dsv, WDT, CIN, 1);

  dim3 cgrid(COUT / BNcT, MROWS / BMr);         // 4 x 245
  const int scanGrid = (NPIX * COUT) / 256;

  conv1b_k<<<cgrid, 256, 0, stream>>>(inp_s, inp_c, W1T, IO);
  scan1_k<<<scanGrid, 256, 0, stream>>>(IO, B1V, vth1, SP, ACT);
  conv2b_k<<<cgrid, 256, 0, stream>>>(SP, ACT, inp_s, inp_c, W2T, WDT, IO);
  final_k<<<scanGrid, 256, 0, stream>>>(IO, B2V, BDV, vthif, out0, out1, out2);
}